// Round 6
// baseline (332.155 us; speedup 1.0000x reference)
//
#include <hip/hip_runtime.h>
#include <cstdint>

typedef __bf16 bf16x8 __attribute__((ext_vector_type(8)));
typedef float floatx4 __attribute__((ext_vector_type(4)));
typedef float floatx16 __attribute__((ext_vector_type(16)));
typedef unsigned short u16;
typedef unsigned int u32;

#define SCALE2 0.1275434297677098f   // (1/sqrt(128)) * log2(e)
#define CLIP2  144.26950408889634f   // 100 * log2(e)
#define DEFER  8.0f                  // defer-max threshold (log2 domain): p <= 2^8

__device__ __forceinline__ u16 f2bf(float f) {
  union { float f; u32 i; } v; v.f = f;
  u32 r = v.i + 0x7fffu + ((v.i >> 16) & 1u);
  return (u16)(r >> 16);
}

// packed f32x2 -> bf16x2 (RNE), dst.lo = bf16(lo), dst.hi = bf16(hi)
__device__ __forceinline__ u32 cvtpk(float lo, float hi) {
  u32 r;
  asm("v_cvt_pk_bf16_f32 %0, %1, %2" : "=v"(r) : "v"(lo), "v"(hi));
  return r;
}

// async global->LDS 16B: per-lane global address, wave-uniform LDS base + lane*16
__device__ __forceinline__ void gll16(const void* g, void* l) {
  __builtin_amdgcn_global_load_lds(
      (const __attribute__((address_space(1))) u32*)g,
      (__attribute__((address_space(3))) u32*)l, 16, 0, 0);
}

// ---------------- fp32 -> bf16 elementwise convert ---------------------------
__global__ __launch_bounds__(256) void convert_bf16(
    const float* __restrict__ src, u16* __restrict__ dst, int n4) {
  int i = blockIdx.x * 256 + threadIdx.x;
  if (i >= n4) return;
  float4 v = ((const float4*)src)[i];
  ushort4 o;
  o.x = f2bf(v.x); o.y = f2bf(v.y); o.z = f2bf(v.z); o.w = f2bf(v.w);
  ((ushort4*)dst)[i] = o;
}

// ---------------- transpose (fp32 in, bf16 out), both weight jobs fused ------
// ny < 80: Wqkv_t (Wq|Wk|Wv concat, N=2560); ny >= 80: Wot (Wo, N=2048).
// Body identical to the verified transpose_cat.
__global__ __launch_bounds__(256) void transpose_all(
    const float* __restrict__ Wq, const float* __restrict__ Wk,
    const float* __restrict__ Wv, const float* __restrict__ Wo,
    u16* __restrict__ Wqkv_t, u16* __restrict__ Wot) {
  __shared__ u16 tile[32][33];
  const int k0 = blockIdx.x * 32, ny = blockIdx.y;
  const float* src; int ld, nb, n0; u16* dst;
  if (ny < 80) {
    n0 = ny * 32; dst = Wqkv_t;
    if (n0 < 2048)      { src = Wq; ld = 2048; nb = n0; }
    else if (n0 < 2304) { src = Wk; ld = 256;  nb = n0 - 2048; }
    else                { src = Wv; ld = 256;  nb = n0 - 2304; }
  } else {
    n0 = (ny - 80) * 32; dst = Wot; src = Wo; ld = 2048; nb = n0;
  }
  const int tx = threadIdx.x, ty = threadIdx.y;
#pragma unroll
  for (int i = 0; i < 4; i++) {
    int k = ty + i * 8;
    tile[k][tx] = f2bf(src[(size_t)(k0 + k) * ld + nb + tx]);
  }
  __syncthreads();
#pragma unroll
  for (int i = 0; i < 4; i++) {
    int n = ty + i * 8;
    dst[(size_t)(n0 + n) * 2048 + k0 + tx] = tile[tx][n];
  }
}

// ---------------- GEMM: C[M,N] = A[M,K] @ Bt[N,K]^T (+bias) ------------------
// 128x128 tile, BK=32, double-buffered LDS, ONE barrier per K-iter.
template <int EPI>
__global__ __launch_bounds__(256) void gemm_bt(
    const u16* __restrict__ A, const u16* __restrict__ Bt,
    const float* __restrict__ bias0, const float* __restrict__ bias1,
    const float* __restrict__ bias2,
    u16* __restrict__ out0, u16* __restrict__ out1, u16* __restrict__ out2,
    float* __restrict__ outf,
    int M, int N, int K) {
  __shared__ u16 As[2][128][32];
  __shared__ u16 Bs[2][128][32];
  const int tid  = threadIdx.x;
  const int w    = tid >> 6, L = tid & 63, ln = L & 15, quad = L >> 4;
  const int m0   = blockIdx.y * 128, n0 = blockIdx.x * 128;
  const int mw   = (w & 1) * 64, nw = (w >> 1) * 64;
  const int sr = w * 32 + (L >> 2), sc = (L & 3) * 8;
  const u16* ga = &A [(size_t)(m0 + sr) * K + sc];
  const u16* gb = &Bt[(size_t)(n0 + sr) * K + sc];
  floatx4 acc[4][4] = {};
  const int nk = K >> 5;

  gll16(ga, &As[0][w * 32][0]);
  gll16(ga + (size_t)16 * K, &As[0][w * 32 + 16][0]);
  gll16(gb, &Bs[0][w * 32][0]);
  gll16(gb + (size_t)16 * K, &Bs[0][w * 32 + 16][0]);

  for (int i = 0; i < nk; i++) {
    const int cur = i & 1;
    __syncthreads();
    if (i + 1 < nk) {
      const int kt = (i + 1) << 5;
      gll16(ga + kt, &As[cur ^ 1][w * 32][0]);
      gll16(ga + (size_t)16 * K + kt, &As[cur ^ 1][w * 32 + 16][0]);
      gll16(gb + kt, &Bs[cur ^ 1][w * 32][0]);
      gll16(gb + (size_t)16 * K + kt, &Bs[cur ^ 1][w * 32 + 16][0]);
    }
    bf16x8 af[4], bf[4];
#pragma unroll
    for (int mb = 0; mb < 4; mb++) af[mb] = *(const bf16x8*)&As[cur][mw + mb * 16 + ln][quad * 8];
#pragma unroll
    for (int nb = 0; nb < 4; nb++) bf[nb] = *(const bf16x8*)&Bs[cur][nw + nb * 16 + ln][quad * 8];
#pragma unroll
    for (int mb = 0; mb < 4; mb++)
#pragma unroll
      for (int nb = 0; nb < 4; nb++)
        acc[mb][nb] = __builtin_amdgcn_mfma_f32_16x16x32_bf16(af[mb], bf[nb], acc[mb][nb], 0, 0, 0);
  }

#pragma unroll
  for (int mb = 0; mb < 4; mb++) {
#pragma unroll
    for (int nb = 0; nb < 4; nb++) {
#pragma unroll
      for (int r = 0; r < 4; r++) {
        const int m = m0 + mw + mb * 16 + quad * 4 + r;
        const int n = n0 + nw + nb * 16 + ln;
        float v = acc[mb][nb][r];
        if constexpr (EPI == 0) {
          if (n < 2048) {            // Q: bf16, pre-scaled by SCALE2
            v = (v + bias0[n]) * SCALE2;
            out0[(size_t)m * 2048 + n] = f2bf(v);
          } else if (n < 2304) {     // K: bf16 [4096][256]
            const int j = n - 2048;
            v += bias1[j];
            out1[(size_t)m * 256 + j] = f2bf(v);
          } else {                   // V transposed: Vt[(b*2+hk)*128+d][t]
            const int j = n - 2304;  // j = hk*128 + d
            v += bias2[j];
            const int b = m >> 11, t = m & 2047;
            out2[((size_t)(b * 256 + j)) * 2048 + t] = f2bf(v);
          }
        } else {
          v += bias0[n];
          outf[(size_t)m * (size_t)N + n] = v;
        }
      }
    }
  }
}

// ---------------- flash attention (S^T, 32x32 MFMA, KVBLK=32, T15) -----------
// DISCRIMINATOR ROUND: identical to round-5 geometry but __launch_bounds__
// (256,2) (VGPR cap 256, no spill pressure). Round-5 failed at (256,4) where
// the 128-VGPR cap forced spills around inline-asm/tied operands; the KVBLK=32
// math is an exact specialization of the round-4-verified recipes. PASS here
// => round-5 was regalloc-pressure corruption, geometry verified (enables
// key-split next). FAIL => logic bug, abandon path.
// Grid (T/128, H, B); 256 threads = 4 waves; wave w owns query rows [w*32,+32).
// Occupancy note: grid = 512 blocks = 2 blocks/CU resident (grid-limited).
__global__ __launch_bounds__(256, 2) void attn_kernel(
    const u16* __restrict__ Q, const u16* __restrict__ K,
    const u16* __restrict__ Vt, u16* __restrict__ O) {
  __shared__ u16 Ksh[2][8 * 512];   // 8 KB per buffer: frag kc holds K[key=ln][16kc+8hf+e]
  __shared__ u16 Vsh[2][8 * 512];   // 8 KB per buffer: frag db*2+ks holds Vt[32db+ln][16ks+8hf+e]
  const int tid = threadIdx.x;
  const int w = tid >> 6, L = tid & 63;
  const int ln = L & 31, hf = L >> 5;
  const int qt = blockIdx.x, h = blockIdx.y, b = blockIdx.z;
  const int hk = h >> 3;  // G = 8
  const size_t qrow0 = (size_t)b * 2048 + qt * 128 + w * 32;

  const u16* Kbase = K + (size_t)b * 2048 * 256 + hk * 128;
  const u16* Vbase = Vt + (size_t)(b * 2 + hk) * 128 * 2048;

  // staging: wave w stages K frags {2w,2w+1} and V frags {2w,2w+1}
  const u16* gK[2];
  const u16* gV[2];
#pragma unroll
  for (int j = 0; j < 2; j++) {
    const int fK = 2 * w + j;                    // = kc
    gK[j] = Kbase + (size_t)ln * 256 + fK * 16 + hf * 8;
    const int fV = 2 * w + j, db = fV >> 1, ks = fV & 1;
    gV[j] = Vbase + (size_t)(db * 32 + ln) * 2048 + ks * 16 + hf * 8;
  }

  // Q B-frags (stationary): B[k=d][n=q]: n = lane&31, k = (lane>>5)*8 + e
  bf16x8 qf[8];
#pragma unroll
  for (int kc = 0; kc < 8; kc++)
    qf[kc] = *(const bf16x8*)&Q[(qrow0 + ln) * 2048 + h * 128 + kc * 16 + hf * 8];

  floatx16 oT[4] = {};               // O^T: col=q=lane&31, row d=32db+(r&3)+8(r>>2)+4hf
  float mrow = -1e30f, lrow = 0.f;   // per-lane (qrow = ln), shared with lane^32

  auto issue = [&](int tile, int bufi) {
#pragma unroll
    for (int j = 0; j < 2; j++) {
      gll16(gK[j] + (size_t)tile * 32 * 256, &Ksh[bufi][(2 * w + j) * 512]);
      gll16(gV[j] + (size_t)tile * 32,       &Vsh[bufi][(2 * w + j) * 512]);
    }
  };

  // S^T = K Q^T : sf C-layout: q=lane&31, key=(r&3)+8(r>>2)+4hf (32 keys/tile)
  auto qkt = [&](floatx16& sf, const u16* kb) {
#pragma unroll
    for (int r = 0; r < 16; r++) sf[r] = 0.f;
#pragma unroll
    for (int kc = 0; kc < 8; kc++) {
      bf16x8 kf = *(const bf16x8*)&kb[kc * 512 + L * 8];
      sf = __builtin_amdgcn_mfma_f32_32x32x16_bf16(kf, qf[kc], sf, 0, 0, 0);
    }
  };

  // clip -> tree-max -> defer-max -> exp2 -> tree-sum -> (rare) oT rescale
  auto softmax = [&](floatx16& sf) {
#pragma unroll
    for (int r = 0; r < 16; r++)
      sf[r] = __builtin_amdgcn_fmed3f(sf[r], -CLIP2, CLIP2);
    float t8[8];
#pragma unroll
    for (int r = 0; r < 8; r++) t8[r] = fmaxf(sf[r], sf[r + 8]);
#pragma unroll
    for (int d = 4; d >= 1; d >>= 1)
#pragma unroll
      for (int r = 0; r < d; r++) t8[r] = fmaxf(t8[r], t8[r + d]);
    const float mx = fmaxf(t8[0], __shfl_xor(t8[0], 32));
    const bool need = __ballot(mx > mrow + DEFER) != 0;   // wave-uniform
    float mn = mrow, alpha = 1.f;
    if (need) {
      mn = fmaxf(mrow, mx);
      alpha = __builtin_amdgcn_exp2f(mrow - mn);
      mrow = mn;
    }
#pragma unroll
    for (int r = 0; r < 16; r++)
      sf[r] = __builtin_amdgcn_exp2f(sf[r] - mn);
    float s8[8];
#pragma unroll
    for (int r = 0; r < 8; r++) s8[r] = sf[r] + sf[r + 8];
#pragma unroll
    for (int d = 4; d >= 1; d >>= 1)
#pragma unroll
      for (int r = 0; r < d; r++) s8[r] += s8[r + d];
    const float s = s8[0] + __shfl_xor(s8[0], 32);
    if (need) {
      lrow = lrow * alpha + s;
#pragma unroll
      for (int db = 0; db < 4; db++)
#pragma unroll
        for (int r = 0; r < 16; r++) oT[db][r] *= alpha;
    } else {
      lrow += s;
    }
  };

  // P^T B-frags via cvt_pk + permlane32_swap (VDST.hi <-> VSRC.lo); O^T=V^T P^T
  // frag ks: lane(ln,hf) needs keys 16ks+8hf+{0..7}; source r = (e&3)+8ks+4hf_t
  // from lane (ln, hf'=e>>2); swap(cA,cB) -> pb = {cA0,cA1,cB0,cB1}.
  auto pv = [&](floatx16& sf, const u16* vb) {
#pragma unroll
    for (int ks = 0; ks < 2; ks++) {
      const int s8p = ks * 8;
      u32 cA0 = cvtpk(sf[s8p + 0], sf[s8p + 1]);
      u32 cA1 = cvtpk(sf[s8p + 2], sf[s8p + 3]);
      u32 cB0 = cvtpk(sf[s8p + 4], sf[s8p + 5]);
      u32 cB1 = cvtpk(sf[s8p + 6], sf[s8p + 7]);
      asm("v_permlane32_swap_b32 %0, %1" : "+v"(cA0), "+v"(cB0));
      asm("v_permlane32_swap_b32 %0, %1" : "+v"(cA1), "+v"(cB1));
      union { u32 u[4]; bf16x8 v; } pb;
      pb.u[0] = cA0; pb.u[1] = cA1; pb.u[2] = cB0; pb.u[3] = cB1;
#pragma unroll
      for (int db = 0; db < 4; db++) {
        bf16x8 vf = *(const bf16x8*)&vb[(db * 2 + ks) * 512 + L * 8];
        oT[db] = __builtin_amdgcn_mfma_f32_32x32x16_bf16(vf, pb.v, oT[db], 0, 0, 0);
      }
    }
  };

  floatx16 sfA, sfB;

  // prologue
  issue(0, 0);
  __syncthreads();                      // drain tile 0
  issue(1, 1);
  qkt(sfA, &Ksh[0][0]);                 // tile 0 scores (loads(1) in flight)

  for (int t = 0; t < 64; t += 2) {
    // ---- tile t (sfA, buf0) ----
    softmax(sfA);
    __syncthreads();                    // drains loads(t+1) -> buf1
    __builtin_amdgcn_s_setprio(1);
    qkt(sfB, &Ksh[1][0]);               // tile t+1 (t <= 62, always valid)
    pv(sfA, &Vsh[0][0]);                // tile t
    __builtin_amdgcn_s_setprio(0);
    __syncthreads();                    // all waves done reading buf0
    if (t + 2 < 64) issue(t + 2, 0);
    // ---- tile t+1 (sfB, buf1) ----
    softmax(sfB);
    __syncthreads();                    // drains loads(t+2) -> buf0
    __builtin_amdgcn_s_setprio(1);
    if (t + 2 < 64) qkt(sfA, &Ksh[0][0]);  // tile t+2
    pv(sfB, &Vsh[1][0]);                // tile t+1
    __builtin_amdgcn_s_setprio(0);
    __syncthreads();                    // all waves done reading buf1
    if (t + 3 < 64) issue(t + 3, 1);
  }

  // ---- epilogue: O[qrow=ln][h*128 + 32db + 8g + 4hf + d4], 8B stores
  const float inv = 1.f / lrow;
  u16* orow = O + (qrow0 + ln) * 2048 + h * 128;
#pragma unroll
  for (int db = 0; db < 4; db++) {
#pragma unroll
    for (int g = 0; g < 4; g++) {
      uint2 st;
      st.x = cvtpk(oT[db][g * 4 + 0] * inv, oT[db][g * 4 + 1] * inv);
      st.y = cvtpk(oT[db][g * 4 + 2] * inv, oT[db][g * 4 + 3] * inv);
      *(uint2*)&orow[db * 32 + g * 8 + hf * 4] = st;
    }
  }
}

extern "C" void kernel_launch(void* const* d_in, const int* in_sizes, int n_in,
                              void* d_out, int out_size, void* d_ws, size_t ws_size,
                              hipStream_t stream) {
  const float* x  = (const float*)d_in[0];
  const float* Wq = (const float*)d_in[1];
  const float* bq = (const float*)d_in[2];
  const float* Wk = (const float*)d_in[3];
  const float* bk = (const float*)d_in[4];
  const float* Wv = (const float*)d_in[5];
  const float* bv = (const float*)d_in[6];
  const float* Wo = (const float*)d_in[7];
  const float* bo = (const float*)d_in[8];
  float* out = (float*)d_out;

  // Workspace layout (bytes). xb is dead after the QKV GEMM, so Ob aliases it.
  char* ws = (char*)d_ws;
  u16* xb     = (u16*)(ws);                      // 4096*2048*2 = 16777216
  u16* Ob     = (u16*)(ws);                      // aliases xb (attn runs after gemm1)
  u16* Wqkv_t = (u16*)(ws + 16777216);           // 2560*2048*2 = 10485760
  u16* Wot    = (u16*)(ws + 27262976);           // 2048*2048*2 =  8388608
  u16* Qb     = (u16*)(ws + 35651584);           // 4096*2048*2 = 16777216
  u16* Kb     = (u16*)(ws + 52428800);           // 4096*256*2  =  2097152
  u16* Vtb    = (u16*)(ws + 54525952);           // 512*2048*2  =  2097152
  (void)in_sizes; (void)n_in; (void)out_size; (void)ws_size;

  convert_bf16<<<8192, 256, 0, stream>>>(x, xb, 2097152);

  transpose_all<<<dim3(64, 144), dim3(32, 8), 0, stream>>>(
      Wq, Wk, Wv, Wo, Wqkv_t, Wot);

  gemm_bt<0><<<dim3(20, 32), 256, 0, stream>>>(
      xb, Wqkv_t, bq, bk, bv, Qb, Kb, Vtb, nullptr, 4096, 2560, 2048);

  attn_kernel<<<dim3(16, 16, 2), 256, 0, stream>>>(Qb, Kb, Vtb, Ob);

  gemm_bt<1><<<dim3(16, 32), 256, 0, stream>>>(
      Ob, Wot, bo, nullptr, nullptr, nullptr, nullptr, nullptr, out, 4096, 2048, 2048);
}

// Round 7
// 327.834 us; speedup vs baseline: 1.0132x; 1.0132x over previous
//
#include <hip/hip_runtime.h>
#include <cstdint>

typedef __bf16 bf16x8 __attribute__((ext_vector_type(8)));
typedef float floatx4 __attribute__((ext_vector_type(4)));
typedef float floatx16 __attribute__((ext_vector_type(16)));
typedef unsigned short u16;
typedef unsigned int u32;

#define SCALE2 0.1275434297677098f   // (1/sqrt(128)) * log2(e)
#define CLIP2  144.26950408889634f   // 100 * log2(e)
#define DEFER  8.0f                  // defer-max threshold (log2 domain): p <= 2^8

__device__ __forceinline__ u16 f2bf(float f) {
  union { float f; u32 i; } v; v.f = f;
  u32 r = v.i + 0x7fffu + ((v.i >> 16) & 1u);
  return (u16)(r >> 16);
}

// packed f32x2 -> bf16x2 (RNE), dst.lo = bf16(lo), dst.hi = bf16(hi)
__device__ __forceinline__ u32 cvtpk(float lo, float hi) {
  u32 r;
  asm("v_cvt_pk_bf16_f32 %0, %1, %2" : "=v"(r) : "v"(lo), "v"(hi));
  return r;
}

// async global->LDS 16B: per-lane global address, wave-uniform LDS base + lane*16
__device__ __forceinline__ void gll16(const void* g, void* l) {
  __builtin_amdgcn_global_load_lds(
      (const __attribute__((address_space(1))) u32*)g,
      (__attribute__((address_space(3))) u32*)l, 16, 0, 0);
}

// counted-vmcnt barrier: drains only the OLDEST outstanding global_load_lds,
// leaving newer prefetches in flight across the barrier (T4).
#define VMBAR(N)                                                   \
  do {                                                             \
    asm volatile("s_waitcnt vmcnt(" #N ")" ::: "memory");          \
    __builtin_amdgcn_s_barrier();                                  \
  } while (0)

// ---------------- fp32 -> bf16 elementwise convert ---------------------------
__global__ __launch_bounds__(256) void convert_bf16(
    const float* __restrict__ src, u16* __restrict__ dst, int n4) {
  int i = blockIdx.x * 256 + threadIdx.x;
  if (i >= n4) return;
  float4 v = ((const float4*)src)[i];
  ushort4 o;
  o.x = f2bf(v.x); o.y = f2bf(v.y); o.z = f2bf(v.z); o.w = f2bf(v.w);
  ((ushort4*)dst)[i] = o;
}

// ---------------- transpose (fp32 in, bf16 out), both weight jobs fused ------
__global__ __launch_bounds__(256) void transpose_all(
    const float* __restrict__ Wq, const float* __restrict__ Wk,
    const float* __restrict__ Wv, const float* __restrict__ Wo,
    u16* __restrict__ Wqkv_t, u16* __restrict__ Wot) {
  __shared__ u16 tile[32][33];
  const int k0 = blockIdx.x * 32, ny = blockIdx.y;
  const float* src; int ld, nb, n0; u16* dst;
  if (ny < 80) {
    n0 = ny * 32; dst = Wqkv_t;
    if (n0 < 2048)      { src = Wq; ld = 2048; nb = n0; }
    else if (n0 < 2304) { src = Wk; ld = 256;  nb = n0 - 2048; }
    else                { src = Wv; ld = 256;  nb = n0 - 2304; }
  } else {
    n0 = (ny - 80) * 32; dst = Wot; src = Wo; ld = 2048; nb = n0;
  }
  const int tx = threadIdx.x, ty = threadIdx.y;
#pragma unroll
  for (int i = 0; i < 4; i++) {
    int k = ty + i * 8;
    tile[k][tx] = f2bf(src[(size_t)(k0 + k) * ld + nb + tx]);
  }
  __syncthreads();
#pragma unroll
  for (int i = 0; i < 4; i++) {
    int n = ty + i * 8;
    dst[(size_t)(n0 + n) * 2048 + k0 + tx] = tile[tx][n];
  }
}

// ---------------- GEMM: C[M,N] = A[M,K] @ Bt[N,K]^T (+bias) ------------------
// 128x128 tile, BK=32, double-buffered LDS, ONE barrier per K-iter.
template <int EPI>
__global__ __launch_bounds__(256) void gemm_bt(
    const u16* __restrict__ A, const u16* __restrict__ Bt,
    const float* __restrict__ bias0, const float* __restrict__ bias1,
    const float* __restrict__ bias2,
    u16* __restrict__ out0, u16* __restrict__ out1, u16* __restrict__ out2,
    float* __restrict__ outf,
    int M, int N, int K) {
  __shared__ u16 As[2][128][32];
  __shared__ u16 Bs[2][128][32];
  const int tid  = threadIdx.x;
  const int w    = tid >> 6, L = tid & 63, ln = L & 15, quad = L >> 4;
  const int m0   = blockIdx.y * 128, n0 = blockIdx.x * 128;
  const int mw   = (w & 1) * 64, nw = (w >> 1) * 64;
  const int sr = w * 32 + (L >> 2), sc = (L & 3) * 8;
  const u16* ga = &A [(size_t)(m0 + sr) * K + sc];
  const u16* gb = &Bt[(size_t)(n0 + sr) * K + sc];
  floatx4 acc[4][4] = {};
  const int nk = K >> 5;

  gll16(ga, &As[0][w * 32][0]);
  gll16(ga + (size_t)16 * K, &As[0][w * 32 + 16][0]);
  gll16(gb, &Bs[0][w * 32][0]);
  gll16(gb + (size_t)16 * K, &Bs[0][w * 32 + 16][0]);

  for (int i = 0; i < nk; i++) {
    const int cur = i & 1;
    __syncthreads();
    if (i + 1 < nk) {
      const int kt = (i + 1) << 5;
      gll16(ga + kt, &As[cur ^ 1][w * 32][0]);
      gll16(ga + (size_t)16 * K + kt, &As[cur ^ 1][w * 32 + 16][0]);
      gll16(gb + kt, &Bs[cur ^ 1][w * 32][0]);
      gll16(gb + (size_t)16 * K + kt, &Bs[cur ^ 1][w * 32 + 16][0]);
    }
    bf16x8 af[4], bf[4];
#pragma unroll
    for (int mb = 0; mb < 4; mb++) af[mb] = *(const bf16x8*)&As[cur][mw + mb * 16 + ln][quad * 8];
#pragma unroll
    for (int nb = 0; nb < 4; nb++) bf[nb] = *(const bf16x8*)&Bs[cur][nw + nb * 16 + ln][quad * 8];
#pragma unroll
    for (int mb = 0; mb < 4; mb++)
#pragma unroll
      for (int nb = 0; nb < 4; nb++)
        acc[mb][nb] = __builtin_amdgcn_mfma_f32_16x16x32_bf16(af[mb], bf[nb], acc[mb][nb], 0, 0, 0);
  }

#pragma unroll
  for (int mb = 0; mb < 4; mb++) {
#pragma unroll
    for (int nb = 0; nb < 4; nb++) {
#pragma unroll
      for (int r = 0; r < 4; r++) {
        const int m = m0 + mw + mb * 16 + quad * 4 + r;
        const int n = n0 + nw + nb * 16 + ln;
        float v = acc[mb][nb][r];
        if constexpr (EPI == 0) {
          if (n < 2048) {            // Q: bf16, pre-scaled by SCALE2
            v = (v + bias0[n]) * SCALE2;
            out0[(size_t)m * 2048 + n] = f2bf(v);
          } else if (n < 2304) {     // K: bf16 [4096][256]
            const int j = n - 2048;
            v += bias1[j];
            out1[(size_t)m * 256 + j] = f2bf(v);
          } else {                   // V transposed: Vt[(b*2+hk)*128+d][t]
            const int j = n - 2304;  // j = hk*128 + d
            v += bias2[j];
            const int b = m >> 11, t = m & 2047;
            out2[((size_t)(b * 256 + j)) * 2048 + t] = f2bf(v);
          }
        } else {
          v += bias0[n];
          outf[(size_t)m * (size_t)N + n] = v;
        }
      }
    }
  }
}

// ---------------- flash attention (4-buffer ring, counted vmcnt) -------------
// Grid (T/128, H, B); 256 threads = 4 waves; wave w owns query rows [w*32,+32).
// KVBLK=32 geometry verified in round 6. Round-6 structural flaw: 2-buffer
// dbuf forces issue(t+2) right before a __syncthreads (vmcnt(0)) with only a
// softmax (~300 cyc) of cover -> per-barrier drain stall (T4 anti-pattern).
// This version: 4-buffer ring (64 KB LDS), issue depth 3, ONE barrier per
// tile with counted vmcnt(4) -- every drained load was issued two full phases
// (~3500 cyc) earlier -> zero-stall waits, half the barriers.
// Schedule per tile: softmax(t) | vmcnt(4); s_barrier | issue(t+3 -> buf[(t+3)&3])
//                    || qkt(t+1, buf[(t+1)&3]) || pv(t, buf[t&3])
// Hazards (enumerated): WAR: issue(t) writes buf[t&3]; last reader pv(t-4)
// is separated by exactly one barrier. RAW: qkt(t+1) needs tile t+1 loads,
// issued at iter t-2, drained by vmcnt(4) (oldest 4 of 8 outstanding).
// LDS-read/overwrite: every ds_read is consumed by an MFMA before the next
// barrier; lgkm ops retire in order => none outstanding at barrier crossing.
__global__ __launch_bounds__(256, 2) void attn_kernel(
    const u16* __restrict__ Q, const u16* __restrict__ K,
    const u16* __restrict__ Vt, u16* __restrict__ O) {
  __shared__ u16 Ksh[4][8 * 512];   // 8 KB per buffer: frag kc holds K[key=ln][16kc+8hf+e]
  __shared__ u16 Vsh[4][8 * 512];   // 8 KB per buffer: frag db*2+ks holds Vt[32db+ln][16ks+8hf+e]
  const int tid = threadIdx.x;
  const int w = tid >> 6, L = tid & 63;
  const int ln = L & 31, hf = L >> 5;
  const int qt = blockIdx.x, h = blockIdx.y, b = blockIdx.z;
  const int hk = h >> 3;  // G = 8
  const size_t qrow0 = (size_t)b * 2048 + qt * 128 + w * 32;

  const u16* Kbase = K + (size_t)b * 2048 * 256 + hk * 128;
  const u16* Vbase = Vt + (size_t)(b * 2 + hk) * 128 * 2048;

  // staging: wave w stages K frags {2w,2w+1} and V frags {2w,2w+1}
  const u16* gK[2];
  const u16* gV[2];
#pragma unroll
  for (int j = 0; j < 2; j++) {
    const int fK = 2 * w + j;                    // = kc
    gK[j] = Kbase + (size_t)ln * 256 + fK * 16 + hf * 8;
    const int fV = 2 * w + j, db = fV >> 1, ks = fV & 1;
    gV[j] = Vbase + (size_t)(db * 32 + ln) * 2048 + ks * 16 + hf * 8;
  }

  // Q B-frags (stationary): B[k=d][n=q]: n = lane&31, k = (lane>>5)*8 + e
  bf16x8 qf[8];
#pragma unroll
  for (int kc = 0; kc < 8; kc++)
    qf[kc] = *(const bf16x8*)&Q[(qrow0 + ln) * 2048 + h * 128 + kc * 16 + hf * 8];

  floatx16 oT[4] = {};               // O^T: col=q=lane&31, row d=32db+(r&3)+8(r>>2)+4hf
  float mrow = -1e30f, lrow = 0.f;   // per-lane (qrow = ln), shared with lane^32

  auto issue = [&](int tile, int bufi) {
#pragma unroll
    for (int j = 0; j < 2; j++) {
      gll16(gK[j] + (size_t)tile * 32 * 256, &Ksh[bufi][(2 * w + j) * 512]);
      gll16(gV[j] + (size_t)tile * 32,       &Vsh[bufi][(2 * w + j) * 512]);
    }
  };

  // S^T = K Q^T : sf C-layout: q=lane&31, key=(r&3)+8(r>>2)+4hf (32 keys/tile)
  auto qkt = [&](floatx16& sf, int bufi) {
#pragma unroll
    for (int r = 0; r < 16; r++) sf[r] = 0.f;
#pragma unroll
    for (int kc = 0; kc < 8; kc++) {
      bf16x8 kf = *(const bf16x8*)&Ksh[bufi][kc * 512 + L * 8];
      sf = __builtin_amdgcn_mfma_f32_32x32x16_bf16(kf, qf[kc], sf, 0, 0, 0);
    }
  };

  // clip -> tree-max -> defer-max -> exp2 -> tree-sum -> (rare) oT rescale
  auto softmax = [&](floatx16& sf) {
#pragma unroll
    for (int r = 0; r < 16; r++)
      sf[r] = __builtin_amdgcn_fmed3f(sf[r], -CLIP2, CLIP2);
    float t8[8];
#pragma unroll
    for (int r = 0; r < 8; r++) t8[r] = fmaxf(sf[r], sf[r + 8]);
#pragma unroll
    for (int d = 4; d >= 1; d >>= 1)
#pragma unroll
      for (int r = 0; r < d; r++) t8[r] = fmaxf(t8[r], t8[r + d]);
    const float mx = fmaxf(t8[0], __shfl_xor(t8[0], 32));
    const bool need = __ballot(mx > mrow + DEFER) != 0;   // wave-uniform
    float mn = mrow, alpha = 1.f;
    if (need) {
      mn = fmaxf(mrow, mx);
      alpha = __builtin_amdgcn_exp2f(mrow - mn);
      mrow = mn;
    }
#pragma unroll
    for (int r = 0; r < 16; r++)
      sf[r] = __builtin_amdgcn_exp2f(sf[r] - mn);
    float s8[8];
#pragma unroll
    for (int r = 0; r < 8; r++) s8[r] = sf[r] + sf[r + 8];
#pragma unroll
    for (int d = 4; d >= 1; d >>= 1)
#pragma unroll
      for (int r = 0; r < d; r++) s8[r] += s8[r + d];
    const float s = s8[0] + __shfl_xor(s8[0], 32);
    if (need) {
      lrow = lrow * alpha + s;
#pragma unroll
      for (int db = 0; db < 4; db++)
#pragma unroll
        for (int r = 0; r < 16; r++) oT[db][r] *= alpha;
    } else {
      lrow += s;
    }
  };

  // P^T B-frags via cvt_pk + permlane32_swap (VDST.hi <-> VSRC.lo); O^T=V^T P^T
  auto pv = [&](floatx16& sf, int bufi) {
#pragma unroll
    for (int ks = 0; ks < 2; ks++) {
      const int s8p = ks * 8;
      u32 cA0 = cvtpk(sf[s8p + 0], sf[s8p + 1]);
      u32 cA1 = cvtpk(sf[s8p + 2], sf[s8p + 3]);
      u32 cB0 = cvtpk(sf[s8p + 4], sf[s8p + 5]);
      u32 cB1 = cvtpk(sf[s8p + 6], sf[s8p + 7]);
      asm("v_permlane32_swap_b32 %0, %1" : "+v"(cA0), "+v"(cB0));
      asm("v_permlane32_swap_b32 %0, %1" : "+v"(cA1), "+v"(cB1));
      union { u32 u[4]; bf16x8 v; } pb;
      pb.u[0] = cA0; pb.u[1] = cA1; pb.u[2] = cB0; pb.u[3] = cB1;
#pragma unroll
      for (int db = 0; db < 4; db++) {
        bf16x8 vf = *(const bf16x8*)&Vsh[bufi][(db * 2 + ks) * 512 + L * 8];
        oT[db] = __builtin_amdgcn_mfma_f32_32x32x16_bf16(vf, pb.v, oT[db], 0, 0, 0);
      }
    }
  };

  floatx16 sfA, sfB;

  // prologue: fill 3-deep, compute tile-0 scores
  issue(0, 0); issue(1, 1); issue(2, 2);
  VMBAR(8);                             // drain tile 0 (tiles 1,2 in flight)
  qkt(sfA, 0);

  // steady: 15 superblocks of 4 tiles; issues t+3..t+6 (max 62 at t=56)
  for (int t = 0; t < 60; t += 4) {
    softmax(sfA); VMBAR(4); issue(t + 3, 3);
    __builtin_amdgcn_s_setprio(1); qkt(sfB, 1); pv(sfA, 0); __builtin_amdgcn_s_setprio(0);
    softmax(sfB); VMBAR(4); issue(t + 4, 0);
    __builtin_amdgcn_s_setprio(1); qkt(sfA, 2); pv(sfB, 1); __builtin_amdgcn_s_setprio(0);
    softmax(sfA); VMBAR(4); issue(t + 5, 1);
    __builtin_amdgcn_s_setprio(1); qkt(sfB, 3); pv(sfA, 2); __builtin_amdgcn_s_setprio(0);
    softmax(sfB); VMBAR(4); issue(t + 6, 2);
    __builtin_amdgcn_s_setprio(1); qkt(sfA, 0); pv(sfB, 3); __builtin_amdgcn_s_setprio(0);
  }
  // tail: tiles 60..63 (outstanding at entry: 61, 62)
  softmax(sfA); VMBAR(4); issue(63, 3);   // drains 61
  __builtin_amdgcn_s_setprio(1); qkt(sfB, 1); pv(sfA, 0); __builtin_amdgcn_s_setprio(0);
  softmax(sfB); VMBAR(4);                 // drains 62
  __builtin_amdgcn_s_setprio(1); qkt(sfA, 2); pv(sfB, 1); __builtin_amdgcn_s_setprio(0);
  softmax(sfA); VMBAR(0);                 // drains 63
  __builtin_amdgcn_s_setprio(1); qkt(sfB, 3); pv(sfA, 2); __builtin_amdgcn_s_setprio(0);
  softmax(sfB);
  pv(sfB, 3);

  // ---- epilogue: O[qrow=ln][h*128 + 32db + 8g + 4hf + d4], 8B stores
  const float inv = 1.f / lrow;
  u16* orow = O + (qrow0 + ln) * 2048 + h * 128;
#pragma unroll
  for (int db = 0; db < 4; db++) {
#pragma unroll
    for (int g = 0; g < 4; g++) {
      uint2 st;
      st.x = cvtpk(oT[db][g * 4 + 0] * inv, oT[db][g * 4 + 1] * inv);
      st.y = cvtpk(oT[db][g * 4 + 2] * inv, oT[db][g * 4 + 3] * inv);
      *(uint2*)&orow[db * 32 + g * 8 + hf * 4] = st;
    }
  }
}

extern "C" void kernel_launch(void* const* d_in, const int* in_sizes, int n_in,
                              void* d_out, int out_size, void* d_ws, size_t ws_size,
                              hipStream_t stream) {
  const float* x  = (const float*)d_in[0];
  const float* Wq = (const float*)d_in[1];
  const float* bq = (const float*)d_in[2];
  const float* Wk = (const float*)d_in[3];
  const float* bk = (const float*)d_in[4];
  const float* Wv = (const float*)d_in[5];
  const float* bv = (const float*)d_in[6];
  const float* Wo = (const float*)d_in[7];
  const float* bo = (const float*)d_in[8];
  float* out = (float*)d_out;

  // Workspace layout (bytes). xb is dead after the QKV GEMM, so Ob aliases it.
  char* ws = (char*)d_ws;
  u16* xb     = (u16*)(ws);                      // 4096*2048*2 = 16777216
  u16* Ob     = (u16*)(ws);                      // aliases xb (attn runs after gemm1)
  u16* Wqkv_t = (u16*)(ws + 16777216);           // 2560*2048*2 = 10485760
  u16* Wot    = (u16*)(ws + 27262976);           // 2048*2048*2 =  8388608
  u16* Qb     = (u16*)(ws + 35651584);           // 4096*2048*2 = 16777216
  u16* Kb     = (u16*)(ws + 52428800);           // 4096*256*2  =  2097152
  u16* Vtb    = (u16*)(ws + 54525952);           // 512*2048*2  =  2097152
  (void)in_sizes; (void)n_in; (void)out_size; (void)ws_size;

  convert_bf16<<<8192, 256, 0, stream>>>(x, xb, 2097152);

  transpose_all<<<dim3(64, 144), dim3(32, 8), 0, stream>>>(
      Wq, Wk, Wv, Wo, Wqkv_t, Wot);

  gemm_bt<0><<<dim3(20, 32), 256, 0, stream>>>(
      xb, Wqkv_t, bq, bk, bv, Qb, Kb, Vtb, nullptr, 4096, 2560, 2048);

  attn_kernel<<<dim3(16, 16, 2), 256, 0, stream>>>(Qb, Kb, Vtb, Ob);

  gemm_bt<1><<<dim3(16, 32), 256, 0, stream>>>(
      Ob, Wot, bo, nullptr, nullptr, nullptr, nullptr, nullptr, out, 4096, 2048, 2048);
}

// Round 8
// 321.032 us; speedup vs baseline: 1.0346x; 1.0212x over previous
//
#include <hip/hip_runtime.h>
#include <cstdint>

typedef __bf16 bf16x8 __attribute__((ext_vector_type(8)));
typedef float floatx4 __attribute__((ext_vector_type(4)));
typedef float floatx16 __attribute__((ext_vector_type(16)));
typedef unsigned short u16;
typedef unsigned int u32;

#define SCALE2 0.1275434297677098f   // (1/sqrt(128)) * log2(e)
#define CLIP2  144.26950408889634f   // 100 * log2(e)
#define DEFER  8.0f                  // defer-max threshold (log2 domain): p <= 2^8

__device__ __forceinline__ u16 f2bf(float f) {
  union { float f; u32 i; } v; v.f = f;
  u32 r = v.i + 0x7fffu + ((v.i >> 16) & 1u);
  return (u16)(r >> 16);
}

// packed f32x2 -> bf16x2 (RNE), dst.lo = bf16(lo), dst.hi = bf16(hi)
__device__ __forceinline__ u32 cvtpk(float lo, float hi) {
  u32 r;
  asm("v_cvt_pk_bf16_f32 %0, %1, %2" : "=v"(r) : "v"(lo), "v"(hi));
  return r;
}

// async global->LDS 16B: per-lane global address, wave-uniform LDS base + lane*16
__device__ __forceinline__ void gll16(const void* g, void* l) {
  __builtin_amdgcn_global_load_lds(
      (const __attribute__((address_space(1))) u32*)g,
      (__attribute__((address_space(3))) u32*)l, 16, 0, 0);
}

// ---------------- fp32 -> bf16 elementwise convert ---------------------------
__global__ __launch_bounds__(256) void convert_bf16(
    const float* __restrict__ src, u16* __restrict__ dst, int n4) {
  int i = blockIdx.x * 256 + threadIdx.x;
  if (i >= n4) return;
  float4 v = ((const float4*)src)[i];
  ushort4 o;
  o.x = f2bf(v.x); o.y = f2bf(v.y); o.z = f2bf(v.z); o.w = f2bf(v.w);
  ((ushort4*)dst)[i] = o;
}

// ---------------- transpose (fp32 in, bf16 out), both weight jobs fused ------
__global__ __launch_bounds__(256) void transpose_all(
    const float* __restrict__ Wq, const float* __restrict__ Wk,
    const float* __restrict__ Wv, const float* __restrict__ Wo,
    u16* __restrict__ Wqkv_t, u16* __restrict__ Wot) {
  __shared__ u16 tile[32][33];
  const int k0 = blockIdx.x * 32, ny = blockIdx.y;
  const float* src; int ld, nb, n0; u16* dst;
  if (ny < 80) {
    n0 = ny * 32; dst = Wqkv_t;
    if (n0 < 2048)      { src = Wq; ld = 2048; nb = n0; }
    else if (n0 < 2304) { src = Wk; ld = 256;  nb = n0 - 2048; }
    else                { src = Wv; ld = 256;  nb = n0 - 2304; }
  } else {
    n0 = (ny - 80) * 32; dst = Wot; src = Wo; ld = 2048; nb = n0;
  }
  const int tx = threadIdx.x, ty = threadIdx.y;
#pragma unroll
  for (int i = 0; i < 4; i++) {
    int k = ty + i * 8;
    tile[k][tx] = f2bf(src[(size_t)(k0 + k) * ld + nb + tx]);
  }
  __syncthreads();
#pragma unroll
  for (int i = 0; i < 4; i++) {
    int n = ty + i * 8;
    dst[(size_t)(n0 + n) * 2048 + k0 + tx] = tile[tx][n];
  }
}

// ---------------- GEMM: C[M,N] = A[M,K] @ Bt[N,K]^T (+bias) ------------------
// 128x128 tile, BK=32, double-buffered LDS, ONE barrier per K-iter.
// T1: bijective XCD-aware block swizzle (NWG must be divisible by 8): blocks
// dispatched to the same XCD (dispatch_id % 8) get a CONTIGUOUS chunk of tile
// space -> A-row panels and B-col panels re-reads hit that XCD's private L2
// instead of re-fetching from L3/HBM on all 8 XCDs.
template <int EPI, int NWG>
__global__ __launch_bounds__(256) void gemm_bt(
    const u16* __restrict__ A, const u16* __restrict__ Bt,
    const float* __restrict__ bias0, const float* __restrict__ bias1,
    const float* __restrict__ bias2,
    u16* __restrict__ out0, u16* __restrict__ out1, u16* __restrict__ out2,
    float* __restrict__ outf,
    int M, int N, int K) {
  __shared__ u16 As[2][128][32];
  __shared__ u16 Bs[2][128][32];
  const int tid  = threadIdx.x;
  const int w    = tid >> 6, L = tid & 63, ln = L & 15, quad = L >> 4;
  // XCD swizzle: lin -> (lin%8)*(NWG/8) + lin/8  (bijective since NWG%8==0)
  const int lin  = blockIdx.x + gridDim.x * blockIdx.y;
  const int swz  = (lin & 7) * (NWG >> 3) + (lin >> 3);
  const int bx   = swz % gridDim.x, by = swz / gridDim.x;
  const int m0   = by * 128, n0 = bx * 128;
  const int mw   = (w & 1) * 64, nw = (w >> 1) * 64;
  const int sr = w * 32 + (L >> 2), sc = (L & 3) * 8;
  const u16* ga = &A [(size_t)(m0 + sr) * K + sc];
  const u16* gb = &Bt[(size_t)(n0 + sr) * K + sc];
  floatx4 acc[4][4] = {};
  const int nk = K >> 5;

  gll16(ga, &As[0][w * 32][0]);
  gll16(ga + (size_t)16 * K, &As[0][w * 32 + 16][0]);
  gll16(gb, &Bs[0][w * 32][0]);
  gll16(gb + (size_t)16 * K, &Bs[0][w * 32 + 16][0]);

  for (int i = 0; i < nk; i++) {
    const int cur = i & 1;
    __syncthreads();
    if (i + 1 < nk) {
      const int kt = (i + 1) << 5;
      gll16(ga + kt, &As[cur ^ 1][w * 32][0]);
      gll16(ga + (size_t)16 * K + kt, &As[cur ^ 1][w * 32 + 16][0]);
      gll16(gb + kt, &Bs[cur ^ 1][w * 32][0]);
      gll16(gb + (size_t)16 * K + kt, &Bs[cur ^ 1][w * 32 + 16][0]);
    }
    bf16x8 af[4], bf[4];
#pragma unroll
    for (int mb = 0; mb < 4; mb++) af[mb] = *(const bf16x8*)&As[cur][mw + mb * 16 + ln][quad * 8];
#pragma unroll
    for (int nb = 0; nb < 4; nb++) bf[nb] = *(const bf16x8*)&Bs[cur][nw + nb * 16 + ln][quad * 8];
#pragma unroll
    for (int mb = 0; mb < 4; mb++)
#pragma unroll
      for (int nb = 0; nb < 4; nb++)
        acc[mb][nb] = __builtin_amdgcn_mfma_f32_16x16x32_bf16(af[mb], bf[nb], acc[mb][nb], 0, 0, 0);
  }

#pragma unroll
  for (int mb = 0; mb < 4; mb++) {
#pragma unroll
    for (int nb = 0; nb < 4; nb++) {
#pragma unroll
      for (int r = 0; r < 4; r++) {
        const int m = m0 + mw + mb * 16 + quad * 4 + r;
        const int n = n0 + nw + nb * 16 + ln;
        float v = acc[mb][nb][r];
        if constexpr (EPI == 0) {
          if (n < 2048) {            // Q: bf16, pre-scaled by SCALE2
            v = (v + bias0[n]) * SCALE2;
            out0[(size_t)m * 2048 + n] = f2bf(v);
          } else if (n < 2304) {     // K: bf16 [4096][256]
            const int j = n - 2048;
            v += bias1[j];
            out1[(size_t)m * 256 + j] = f2bf(v);
          } else {                   // V transposed: Vt[(b*2+hk)*128+d][t]
            const int j = n - 2304;  // j = hk*128 + d
            v += bias2[j];
            const int b = m >> 11, t = m & 2047;
            out2[((size_t)(b * 256 + j)) * 2048 + t] = f2bf(v);
          }
        } else {
          v += bias0[n];
          outf[(size_t)m * (size_t)N + n] = v;
        }
      }
    }
  }
}

// ---------------- flash attention (S^T, 32x32 MFMA, KVBLK=64, T15) -----------
// CHAMPION REVERT: exact round-4 structure (92.0 us measured). Three structural
// experiments since: T15 double-pipeline (+15%, kept), KVBLK=32 (-6%, dropped),
// 4-buffer counted-vmcnt ring (-2%, dropped). The vmcnt drains were already
// covered by the softmax phase; KVBLK=32's per-tile fixed costs are a tax.
// Grid (T/128, H, B); 256 threads = 4 waves; wave w owns query rows [w*32,+32).
// Schedule per tile-pair: softmax(t)|BAR|[qkt(t+1)||pv(t)]|BAR|issue(t+2)|...
__global__ __launch_bounds__(256, 2) void attn_kernel(
    const u16* __restrict__ Q, const u16* __restrict__ K,
    const u16* __restrict__ Vt, u16* __restrict__ O) {
  __shared__ u16 Ksh[2][16 * 512];   // 32 KB: 16 frags of 1KB (frag-major)
  __shared__ u16 Vsh[2][16 * 512];   // 32 KB
  const int tid = threadIdx.x;
  const int w = tid >> 6, L = tid & 63;
  const int ln = L & 31, hf = L >> 5;
  const int qt = blockIdx.x, h = blockIdx.y, b = blockIdx.z;
  const int hk = h >> 3;  // G = 8
  const size_t qrow0 = (size_t)b * 2048 + qt * 128 + w * 32;

  const u16* Kbase = K + (size_t)b * 2048 * 256 + hk * 128;
  const u16* Vbase = Vt + (size_t)(b * 2 + hk) * 128 * 2048;

  // staging: wave w stages K frags {4w..4w+3} and V frags {4w..4w+3}.
  // K frag fK = mb*8+kc holds K[32mb + (L&31)][16kc + (L>>5)*8 + e] (A-frag).
  // V frag fV = db*4+ks holds V^T[32db + (L&31)][16ks + (L>>5)*8 + e] (A-frag).
  const u16* gK[4];
  const u16* gV[4];
#pragma unroll
  for (int j = 0; j < 4; j++) {
    const int fK = 4 * w + j, mb = fK >> 3, kc = fK & 7;
    gK[j] = Kbase + (size_t)(mb * 32 + ln) * 256 + kc * 16 + hf * 8;
    const int fV = 4 * w + j, db = fV >> 2, ks = fV & 3;
    gV[j] = Vbase + (size_t)(db * 32 + ln) * 2048 + ks * 16 + hf * 8;
  }

  // Q B-frags (stationary): B[k=d][n=q]: n = lane&31, k = (lane>>5)*8 + e
  bf16x8 qf[8];
#pragma unroll
  for (int kc = 0; kc < 8; kc++)
    qf[kc] = *(const bf16x8*)&Q[(qrow0 + ln) * 2048 + h * 128 + kc * 16 + hf * 8];

  floatx16 oT[4] = {};               // O^T: col=q=lane&31, row d=32db+(r&3)+8(r>>2)+4hf
  float mrow = -1e30f, lrow = 0.f;   // per-lane (qrow = ln), shared with lane^32

  auto issue = [&](int tile, int bufi) {
#pragma unroll
    for (int j = 0; j < 4; j++) {
      gll16(gK[j] + (size_t)tile * 64 * 256, &Ksh[bufi][(4 * w + j) * 512]);
      gll16(gV[j] + (size_t)tile * 64,       &Vsh[bufi][(4 * w + j) * 512]);
    }
  };

  // S^T = K Q^T : sf[mb] C-layout: q=lane&31, key=32mb+(r&3)+8(r>>2)+4hf
  auto qkt = [&](floatx16 (&sf)[2], const u16* kb) {
#pragma unroll
    for (int r = 0; r < 16; r++) { sf[0][r] = 0.f; sf[1][r] = 0.f; }
#pragma unroll
    for (int kc = 0; kc < 8; kc++) {
#pragma unroll
      for (int mb = 0; mb < 2; mb++) {
        bf16x8 kf = *(const bf16x8*)&kb[(mb * 8 + kc) * 512 + L * 8];
        sf[mb] = __builtin_amdgcn_mfma_f32_32x32x16_bf16(kf, qf[kc], sf[mb], 0, 0, 0);
      }
    }
  };

  // clip -> tree-max -> defer-max -> exp2 -> tree-sum -> (rare) oT rescale
  auto softmax = [&](floatx16 (&sf)[2]) {
#pragma unroll
    for (int mb = 0; mb < 2; mb++)
#pragma unroll
      for (int r = 0; r < 16; r++)
        sf[mb][r] = __builtin_amdgcn_fmed3f(sf[mb][r], -CLIP2, CLIP2);
    float t16[16];
#pragma unroll
    for (int r = 0; r < 16; r++) t16[r] = fmaxf(sf[0][r], sf[1][r]);
#pragma unroll
    for (int d = 8; d >= 1; d >>= 1)
#pragma unroll
      for (int r = 0; r < d; r++) t16[r] = fmaxf(t16[r], t16[r + d]);
    const float mx = fmaxf(t16[0], __shfl_xor(t16[0], 32));
    const bool need = __ballot(mx > mrow + DEFER) != 0;   // wave-uniform
    float mn = mrow, alpha = 1.f;
    if (need) {
      mn = fmaxf(mrow, mx);
      alpha = __builtin_amdgcn_exp2f(mrow - mn);
      mrow = mn;
    }
#pragma unroll
    for (int mb = 0; mb < 2; mb++)
#pragma unroll
      for (int r = 0; r < 16; r++)
        sf[mb][r] = __builtin_amdgcn_exp2f(sf[mb][r] - mn);
    float s16[16];
#pragma unroll
    for (int r = 0; r < 16; r++) s16[r] = sf[0][r] + sf[1][r];
#pragma unroll
    for (int d = 8; d >= 1; d >>= 1)
#pragma unroll
      for (int r = 0; r < d; r++) s16[r] += s16[r + d];
    const float s = s16[0] + __shfl_xor(s16[0], 32);
    if (need) {
      lrow = lrow * alpha + s;
#pragma unroll
      for (int db = 0; db < 4; db++)
#pragma unroll
        for (int r = 0; r < 16; r++) oT[db][r] *= alpha;
    } else {
      lrow += s;
    }
  };

  // P^T B-frags via cvt_pk + permlane32_swap (VDST.hi <-> VSRC.lo); O^T=V^T P^T
  auto pv = [&](floatx16 (&sf)[2], const u16* vb) {
#pragma unroll
    for (int ks = 0; ks < 4; ks++) {
      const int mb = ks >> 1, s8 = (ks & 1) * 8;
      u32 cA0 = cvtpk(sf[mb][s8 + 0], sf[mb][s8 + 1]);
      u32 cA1 = cvtpk(sf[mb][s8 + 2], sf[mb][s8 + 3]);
      u32 cB0 = cvtpk(sf[mb][s8 + 4], sf[mb][s8 + 5]);
      u32 cB1 = cvtpk(sf[mb][s8 + 6], sf[mb][s8 + 7]);
      asm("v_permlane32_swap_b32 %0, %1" : "+v"(cA0), "+v"(cB0));
      asm("v_permlane32_swap_b32 %0, %1" : "+v"(cA1), "+v"(cB1));
      union { u32 u[4]; bf16x8 v; } pb;
      pb.u[0] = cA0; pb.u[1] = cA1; pb.u[2] = cB0; pb.u[3] = cB1;
#pragma unroll
      for (int db = 0; db < 4; db++) {
        bf16x8 vf = *(const bf16x8*)&vb[(db * 4 + ks) * 512 + L * 8];
        oT[db] = __builtin_amdgcn_mfma_f32_32x32x16_bf16(vf, pb.v, oT[db], 0, 0, 0);
      }
    }
  };

  floatx16 sfA[2], sfB[2];

  // prologue
  issue(0, 0);
  __syncthreads();                      // drain tile 0
  issue(1, 1);
  qkt(sfA, &Ksh[0][0]);                 // tile 0 scores (loads(1) in flight)

  for (int t = 0; t < 32; t += 2) {
    // ---- tile t (sfA, buf0) ----
    softmax(sfA);
    __syncthreads();                    // drains loads(t+1) -> buf1
    __builtin_amdgcn_s_setprio(1);
    qkt(sfB, &Ksh[1][0]);               // tile t+1 (t <= 30, always valid)
    pv(sfA, &Vsh[0][0]);                // tile t
    __builtin_amdgcn_s_setprio(0);
    __syncthreads();                    // all waves done reading buf0
    if (t + 2 < 32) issue(t + 2, 0);
    // ---- tile t+1 (sfB, buf1) ----
    softmax(sfB);
    __syncthreads();                    // drains loads(t+2) -> buf0
    __builtin_amdgcn_s_setprio(1);
    if (t + 2 < 32) qkt(sfA, &Ksh[0][0]);  // tile t+2
    pv(sfB, &Vsh[1][0]);                // tile t+1
    __builtin_amdgcn_s_setprio(0);
    __syncthreads();                    // all waves done reading buf1
    if (t + 3 < 32) issue(t + 3, 1);
  }

  // ---- epilogue: O[qrow=ln][h*128 + 32db + 8g + 4hf + d4], 8B stores
  const float inv = 1.f / lrow;
  u16* orow = O + (qrow0 + ln) * 2048 + h * 128;
#pragma unroll
  for (int db = 0; db < 4; db++) {
#pragma unroll
    for (int g = 0; g < 4; g++) {
      uint2 st;
      st.x = cvtpk(oT[db][g * 4 + 0] * inv, oT[db][g * 4 + 1] * inv);
      st.y = cvtpk(oT[db][g * 4 + 2] * inv, oT[db][g * 4 + 3] * inv);
      *(uint2*)&orow[db * 32 + g * 8 + hf * 4] = st;
    }
  }
}

extern "C" void kernel_launch(void* const* d_in, const int* in_sizes, int n_in,
                              void* d_out, int out_size, void* d_ws, size_t ws_size,
                              hipStream_t stream) {
  const float* x  = (const float*)d_in[0];
  const float* Wq = (const float*)d_in[1];
  const float* bq = (const float*)d_in[2];
  const float* Wk = (const float*)d_in[3];
  const float* bk = (const float*)d_in[4];
  const float* Wv = (const float*)d_in[5];
  const float* bv = (const float*)d_in[6];
  const float* Wo = (const float*)d_in[7];
  const float* bo = (const float*)d_in[8];
  float* out = (float*)d_out;

  // Workspace layout (bytes). xb is dead after the QKV GEMM, so Ob aliases it.
  char* ws = (char*)d_ws;
  u16* xb     = (u16*)(ws);                      // 4096*2048*2 = 16777216
  u16* Ob     = (u16*)(ws);                      // aliases xb (attn runs after gemm1)
  u16* Wqkv_t = (u16*)(ws + 16777216);           // 2560*2048*2 = 10485760
  u16* Wot    = (u16*)(ws + 27262976);           // 2048*2048*2 =  8388608
  u16* Qb     = (u16*)(ws + 35651584);           // 4096*2048*2 = 16777216
  u16* Kb     = (u16*)(ws + 52428800);           // 4096*256*2  =  2097152
  u16* Vtb    = (u16*)(ws + 54525952);           // 512*2048*2  =  2097152
  (void)in_sizes; (void)n_in; (void)out_size; (void)ws_size;

  convert_bf16<<<8192, 256, 0, stream>>>(x, xb, 2097152);

  transpose_all<<<dim3(64, 144), dim3(32, 8), 0, stream>>>(
      Wq, Wk, Wv, Wo, Wqkv_t, Wot);

  gemm_bt<0, 640><<<dim3(20, 32), 256, 0, stream>>>(
      xb, Wqkv_t, bq, bk, bv, Qb, Kb, Vtb, nullptr, 4096, 2560, 2048);

  attn_kernel<<<dim3(16, 16, 2), 256, 0, stream>>>(Qb, Kb, Vtb, Ob);

  gemm_bt<1, 512><<<dim3(16, 32), 256, 0, stream>>>(
      Ob, Wot, bo, nullptr, nullptr, nullptr, nullptr, nullptr, out, 4096, 2048, 2048);
}